// Round 16
// baseline (2300.424 us; speedup 1.0000x reference)
//
#include <hip/hip_runtime.h>

#define B_  4096
#define T_  2048
#define H1_ 32
#define H2_ 16
#define RPB 4   // waves per block (256 threads); waves never interact
#define RPW 2   // independent rows per wave (R11-proven best; grid-capped at 2 waves/SIMD)

#define LOG2E     1.44269504088896340736f
#define TWOLOG2E  2.88539008177792681472f

typedef float f32x2 __attribute__((ext_vector_type(2)));
typedef float f32x4 __attribute__((ext_vector_type(4)));

// packed fp32 fma (R5-proven exact; lowers to v_pk_fma_f32)
#if defined(__has_builtin)
#if __has_builtin(__builtin_elementwise_fma)
#define PKFMA(acc, a, b) (acc) = __builtin_elementwise_fma((a), (b), (acc))
#endif
#endif
#ifndef PKFMA
#define PKFMA(acc, a, b) (acc) = (a) * (b) + (acc)
#endif

// Wave-local LDS ordering fences (R9/R11/R14/R15-proven, replaces __syncthreads)
#define FENCE_HW() asm volatile("s_waitcnt lgkmcnt(0)" ::: "memory")
#define FENCE_SW() asm volatile("" ::: "memory")

__device__ __forceinline__ float sig_core(float z) {
    return __builtin_amdgcn_rcpf(1.0f + __builtin_amdgcn_exp2f(-z));
}

// ---- ws layout (floats), all pre-scaled by log2e / 2log2e ----
#define WS_W1   0
#define WS_W2A  4096
#define WS_W2B  6144
#define WS_WX   7168
#define WS_B1   7296
#define WS_B2   7424
#define WS_N    7488

__device__ __forceinline__ float scale1(int r) {
    return (r >= 64 && r < 96) ? TWOLOG2E : LOG2E;
}
__device__ __forceinline__ float scale2(int r) {
    return ((r >> 4) == 2) ? TWOLOG2E : LOG2E;
}

__global__ __launch_bounds__(256) void prescale_kernel(
    const float* __restrict__ W_ih1, const float* __restrict__ W_hh1,
    const float* __restrict__ b_ih1, const float* __restrict__ b_hh1,
    const float* __restrict__ W_ih2, const float* __restrict__ W_hh2,
    const float* __restrict__ b_ih2, const float* __restrict__ b_hh2,
    float* __restrict__ ws)
{
    const int i = blockIdx.x * 256 + threadIdx.x;
    if (i >= WS_N) return;
    float v;
    if (i < WS_W2A) {
        v = W_hh1[i] * scale1(i >> 5);
    } else if (i < WS_W2B) {
        const int j = i - WS_W2A;
        v = W_ih2[j] * scale2(j >> 5);
    } else if (i < WS_WX) {
        const int j = i - WS_W2B;
        v = W_hh2[j] * scale2(j >> 4);
    } else if (i < WS_B1) {
        const int r = i - WS_WX;
        v = W_ih1[r] * scale1(r);
    } else if (i < WS_B2) {
        const int r = i - WS_B1;
        v = (b_ih1[r] + b_hh1[r]) * scale1(r);
    } else {
        const int r = i - WS_B2;
        v = (b_ih2[r] + b_hh2[r]) * scale2(r);
    }
    ws[i] = v;
}

__global__ __launch_bounds__(64 * RPB, 2) void lstm_deep_kernel(
    const float* __restrict__ x,
    const float* __restrict__ ws,     // pre-scaled weights/biases
    const float* __restrict__ W_out,
    const float* __restrict__ b_out,
    float* __restrict__ out)
{
    const int tid  = threadIdx.x;
    const int lane = tid & 63;
    const int wid  = tid >> 6;                        // wave within block
    const int row0 = (blockIdx.x * RPB + wid) * RPW;  // 2 rows per wave
    const int row1 = row0 + 1;

    // per-wave, per-row PRIVATE LDS; fence-ordered (no __syncthreads)
    __shared__ __align__(16) float sh1[RPB][RPW][H1_];
    __shared__ __align__(16) float sh2[RPB][RPW][2][H2_];   // h2 double buffer

    const int ga = lane;        // layer1 rows: i (low) / f (high)
    const int gb = 64 + lane;   // layer1 rows: g (low, tanh) / o (high)

    const f32x2* W1p  = reinterpret_cast<const f32x2*>(ws + WS_W1);
    const f32x2* W2ap = reinterpret_cast<const f32x2*>(ws + WS_W2A);
    const f32x2* W2bp = reinterpret_cast<const f32x2*>(ws + WS_W2B);

    f32x2 w1a[H1_ / 2], w1b[H1_ / 2];
    #pragma unroll
    for (int j = 0; j < H1_ / 2; ++j) {
        w1a[j] = W1p[ga * (H1_ / 2) + j];
        w1b[j] = W1p[gb * (H1_ / 2) + j];
    }
    f32x2 w2a[H1_ / 2];
    #pragma unroll
    for (int j = 0; j < H1_ / 2; ++j) w2a[j] = W2ap[lane * (H1_ / 2) + j];
    f32x2 w2b[H2_ / 2];
    #pragma unroll
    for (int j = 0; j < H2_ / 2; ++j) w2b[j] = W2bp[lane * (H2_ / 2) + j];

    float wxa = ws[WS_WX + ga];
    float wxb = ws[WS_WX + gb];
    float ba  = ws[WS_B1 + ga];
    float bb  = ws[WS_B1 + gb];
    float b2  = ws[WS_B2 + lane];

    // one-time opaque pin (R14/R15-proven: keeps weights resident, no remat)
    #pragma unroll
    for (int j = 0; j < H1_ / 2; ++j)
        asm volatile("" : "+v"(w1a[j]), "+v"(w1b[j]), "+v"(w2a[j]));
    #pragma unroll
    for (int j = 0; j < H2_ / 2; ++j)
        asm volatile("" : "+v"(w2b[j]));
    asm volatile("" : "+v"(wxa), "+v"(wxb), "+v"(ba), "+v"(bb), "+v"(b2));

    const bool  low  = (lane < 32);
    const int   gt   = lane >> 4;
    const float sc1b = low ? 2.0f : 1.0f;
    const float of1b = low ? -1.0f : 0.0f;
    const float sc2c = (gt == 2) ? 2.0f : 1.0f;
    const float of2c = (gt == 2) ? -1.0f : 0.0f;

    const int   u2   = lane & 15;
    const float wout = W_out[u2];
    const float bout = b_out[0];

    // ---- state ----
    float c1_0 = 0.0f, c1_1 = 0.0f;   // valid in high lanes (unit lane-32)
    float c2_0 = 0.0f, c2_1 = 0.0f;   // valid in lanes 0..15 (unit u2)
    if (lane < H1_) { sh1[wid][0][lane] = 0.0f; sh1[wid][1][lane] = 0.0f; }
    if (lane < H2_) {
        sh2[wid][0][0][lane] = 0.0f; sh2[wid][0][1][lane] = 0.0f;
        sh2[wid][1][0][lane] = 0.0f; sh2[wid][1][1][lane] = 0.0f;
    }
    FENCE_HW();   // init visible before first-step reads (wave-local)

    const f32x4* __restrict__ xr0 = reinterpret_cast<const f32x4*>(x + (size_t)row0 * T_);
    const f32x4* __restrict__ xr1 = reinterpret_cast<const f32x4*>(x + (size_t)row1 * T_);
    float*       __restrict__ or0 = out + (size_t)row0 * T_;
    float*       __restrict__ or1 = out + (size_t)row1 * T_;

    // carried layer-1 gate accumulators, pre-seeded for t=0 (h1_{-1}=0)
    f32x4 xv0 = xr0[0];
    f32x4 xv1 = xr1[0];
    f32x2 A0c = {__builtin_fmaf(wxa, xv0.x, ba), 0.0f};
    f32x2 B0c = {__builtin_fmaf(wxb, xv0.x, bb), 0.0f};
    f32x2 A1c = {__builtin_fmaf(wxa, xv1.x, ba), 0.0f};
    f32x2 B1c = {__builtin_fmaf(wxb, xv1.x, bb), 0.0f};

    // one timestep for BOTH rows. nxt* = x of NEXT step (pipelined layer-1).
    // par = this step's sh2 write buffer; reads sh2[par^1] (last step's).
    auto step2 = [&](float nxt0, float nxt1, int par, float& yp0, float& yp1) {
        // ---- layer-1 activations from CARRIED accumulators (step starts hot) ----
        const float acca0 = A0c.x + A0c.y, accb0 = B0c.x + B0c.y;
        const float acca1 = A1c.x + A1c.y, accb1 = B1c.x + B1c.y;

        const float sa0 = sig_core(acca0);
        const float sa1 = sig_core(acca1);
        const float sb0 = __builtin_fmaf(sc1b, sig_core(accb0), of1b);
        const float sb1 = __builtin_fmaf(sc1b, sig_core(accb1), of1b);
        const float pv0 = __shfl_xor(sa0 * sb0, 32);
        const float pv1 = __shfl_xor(sa1 * sb1, 32);
        c1_0 = __builtin_fmaf(sa0, c1_0, pv0);
        c1_1 = __builtin_fmaf(sa1, c1_1, pv1);
        const float tc10 = __builtin_fmaf(2.0f, sig_core(TWOLOG2E * c1_0), -1.0f);
        const float tc11 = __builtin_fmaf(2.0f, sig_core(TWOLOG2E * c1_1), -1.0f);
        const float h1n0 = sb0 * tc10;   // valid lanes 32..63
        const float h1n1 = sb1 * tc11;

        if (lane >= 32) {
            sh1[wid][0][lane - 32] = h1n0;
            sh1[wid][1][lane - 32] = h1n1;
        }

        // ---- layer-2 h2-part from DOUBLE-BUFFERED LDS (R14-proven overlap):
        //      sh2[par^1] was written last step (pre-last-FENCE_SW); these
        //      ds_reads issue alongside the activation chain above, zero VALU.
        f32x2 E0 = {b2, 0.0f}, F0 = {0.0f, 0.0f};
        f32x2 E1 = {b2, 0.0f}, F1 = {0.0f, 0.0f};
        {
            const f32x4* q0 = reinterpret_cast<const f32x4*>(sh2[wid][0][par ^ 1]);
            const f32x4* q1 = reinterpret_cast<const f32x4*>(sh2[wid][1][par ^ 1]);
            #pragma unroll
            for (int q = 0; q < H2_ / 4; ++q) {
                const f32x4 v0 = q0[q];
                const f32x4 v1 = q1[q];
                const f32x2 va01 = {v0.x, v0.y}, va23 = {v0.z, v0.w};
                const f32x2 vb01 = {v1.x, v1.y}, vb23 = {v1.z, v1.w};
                PKFMA(E0, w2b[2 * q],     va01);
                PKFMA(F0, w2b[2 * q + 1], va23);
                PKFMA(E1, w2b[2 * q],     vb01);
                PKFMA(F1, w2b[2 * q + 1], vb23);
            }
        }

        FENCE_HW();   // sh1 writes complete; no sh1 read hoisted above

        // refill carried layer-1 accumulators with NEXT step's x
        A0c = f32x2{__builtin_fmaf(wxa, nxt0, ba), 0.0f};
        B0c = f32x2{__builtin_fmaf(wxb, nxt0, bb), 0.0f};
        A1c = f32x2{__builtin_fmaf(wxa, nxt1, ba), 0.0f};
        B1c = f32x2{__builtin_fmaf(wxb, nxt1, bb), 0.0f};

        // ---- SINGLE sh1 read region: layer-2 h1-part AND next-step layer-1 ----
        {
            const f32x4* p0 = reinterpret_cast<const f32x4*>(sh1[wid][0]);
            const f32x4* p1 = reinterpret_cast<const f32x4*>(sh1[wid][1]);
            #pragma unroll
            for (int q = 0; q < H1_ / 4; ++q) {
                const f32x4 v0 = p0[q];
                const f32x4 v1 = p1[q];
                const f32x2 a01 = {v0.x, v0.y}, a23 = {v0.z, v0.w};
                const f32x2 b01 = {v1.x, v1.y}, b23 = {v1.z, v1.w};
                PKFMA(E0,  w2a[2 * q],     a01);
                PKFMA(F0,  w2a[2 * q + 1], a23);
                PKFMA(E1,  w2a[2 * q],     b01);
                PKFMA(F1,  w2a[2 * q + 1], b23);
                PKFMA(A0c, w1a[2 * q],     a01);
                PKFMA(A0c, w1a[2 * q + 1], a23);
                PKFMA(B0c, w1b[2 * q],     a01);
                PKFMA(B0c, w1b[2 * q + 1], a23);
                PKFMA(A1c, w1a[2 * q],     b01);
                PKFMA(A1c, w1a[2 * q + 1], b23);
                PKFMA(B1c, w1b[2 * q],     b01);
                PKFMA(B1c, w1b[2 * q + 1], b23);
            }
        }
        const float d20 = (E0.x + E0.y) + (F0.x + F0.y);
        const float d21 = (E1.x + E1.y) + (F1.x + F1.y);

        const float s20 = __builtin_fmaf(sc2c, sig_core(d20), of2c);
        const float s21 = __builtin_fmaf(sc2c, sig_core(d21), of2c);
        // gate combine, valid in lanes 0..15 (XOR patterns: swizzle-friendly)
        const float t320 = s20 * __shfl_xor(s20, 32);
        const float t321 = s21 * __shfl_xor(s21, 32);
        const float sf0  = __shfl_xor(s20, 16), sf1 = __shfl_xor(s21, 16);
        const float so0  = __shfl_xor(s20, 48), so1 = __shfl_xor(s21, 48);

        c2_0 = __builtin_fmaf(sf0, c2_0, t320);
        c2_1 = __builtin_fmaf(sf1, c2_1, t321);
        const float tc20 = __builtin_fmaf(2.0f, sig_core(TWOLOG2E * c2_0), -1.0f);
        const float tc21 = __builtin_fmaf(2.0f, sig_core(TWOLOG2E * c2_1), -1.0f);
        const float h2v0 = so0 * tc20;   // valid lanes 0..15
        const float h2v1 = so1 * tc21;

        if (lane < H2_) {
            sh2[wid][0][par][lane] = h2v0;   // consumed next step, pre-fence
            sh2[wid][1][par][lane] = h2v1;
        }
        FENCE_SW();   // step boundary: no cross-step LDS reorder (zero instr)

        yp0 = wout * h2v0;   // garbage in lanes >=16; group-0 reduce discards
        yp1 = wout * h2v1;
    };

    #pragma unroll 1
    for (int t4 = 0; t4 < T_ / 4; ++t4) {
        const int nx = (t4 + 1 < T_ / 4) ? (t4 + 1) : t4;
        const f32x4 xn0 = xr0[nx];    // prefetch next 4 inputs, both rows
        const f32x4 xn1 = xr1[nx];

        float p00, p10, p01, p11, p02, p12, p03, p13;
        step2(xv0.y, xv1.y, 0, p00, p10);   // step 4t+0; preps A for 4t+1
        step2(xv0.z, xv1.z, 1, p01, p11);
        step2(xv0.w, xv1.w, 0, p02, p12);
        step2(xn0.x, xn1.x, 1, p03, p13);   // step 4t+3; preps A for 4(t+1)

        // 8 interleaved 16-lane xor reductions (lane 0 of group 0 is used)
        #pragma unroll
        for (int off = 1; off <= 8; off <<= 1) {
            p00 += __shfl_xor(p00, off);  p10 += __shfl_xor(p10, off);
            p01 += __shfl_xor(p01, off);  p11 += __shfl_xor(p11, off);
            p02 += __shfl_xor(p02, off);  p12 += __shfl_xor(p12, off);
            p03 += __shfl_xor(p03, off);  p13 += __shfl_xor(p13, off);
        }

        if (lane == 0) {
            f32x4 y0 = {p00 + bout, p01 + bout, p02 + bout, p03 + bout};
            f32x4 y1 = {p10 + bout, p11 + bout, p12 + bout, p13 + bout};
            *reinterpret_cast<f32x4*>(or0 + 4 * t4) = y0;
            *reinterpret_cast<f32x4*>(or1 + 4 * t4) = y1;
        }
        xv0 = xn0;
        xv1 = xn1;
    }
}

extern "C" void kernel_launch(void* const* d_in, const int* in_sizes, int n_in,
                              void* d_out, int out_size, void* d_ws, size_t ws_size,
                              hipStream_t stream) {
    const float* xp     = (const float*)d_in[0];
    const float* W_ih1  = (const float*)d_in[1];
    const float* W_hh1  = (const float*)d_in[2];
    const float* b_ih1  = (const float*)d_in[3];
    const float* b_hh1  = (const float*)d_in[4];
    const float* W_ih2  = (const float*)d_in[5];
    const float* W_hh2  = (const float*)d_in[6];
    const float* b_ih2  = (const float*)d_in[7];
    const float* b_hh2  = (const float*)d_in[8];
    const float* W_out  = (const float*)d_in[9];
    const float* b_out  = (const float*)d_in[10];
    float* out = (float*)d_out;
    float* ws  = (float*)d_ws;

    prescale_kernel<<<(WS_N + 255) / 256, 256, 0, stream>>>(
        W_ih1, W_hh1, b_ih1, b_hh1, W_ih2, W_hh2, b_ih2, b_hh2, ws);

    dim3 grid(B_ / (RPB * RPW));
    dim3 block(64 * RPB);
    lstm_deep_kernel<<<grid, block, 0, stream>>>(xp, ws, W_out, b_out, out);
}

// Round 18
// 2296.064 us; speedup vs baseline: 1.0019x; 1.0019x over previous
//
#include <hip/hip_runtime.h>

#define B_  4096
#define T_  2048
#define H1_ 32
#define H2_ 16
#define RPB 4   // waves per block (256 threads); waves never interact
#define RPW 2   // independent rows per wave (R11-proven best)

#define LOG2E     1.44269504088896340736f
#define TWOLOG2E  2.88539008177792681472f

typedef float f32x2 __attribute__((ext_vector_type(2)));
typedef float f32x4 __attribute__((ext_vector_type(4)));

// packed fp32 fma (R5-proven exact; lowers to v_pk_fma_f32)
#if defined(__has_builtin)
#if __has_builtin(__builtin_elementwise_fma)
#define PKFMA(acc, a, b) (acc) = __builtin_elementwise_fma((a), (b), (acc))
#endif
#endif
#ifndef PKFMA
#define PKFMA(acc, a, b) (acc) = (a) * (b) + (acc)
#endif

// Wave-local LDS ordering fences (R9/R11/R14/R15-proven)
#define FENCE_HW() asm volatile("s_waitcnt lgkmcnt(0)" ::: "memory")
#define FENCE_SW() asm volatile("" ::: "memory")

__device__ __forceinline__ float sig_core(float z) {
    return __builtin_amdgcn_rcpf(1.0f + __builtin_amdgcn_exp2f(-z));
}
// wave-uniform broadcast: physical-lane read -> SGPR (R15-proven)
__device__ __forceinline__ float lane_bcast(float v, int srcLane) {
    return __uint_as_float(__builtin_amdgcn_readlane(__float_as_uint(v), srcLane));
}
// literal-pattern LDS swizzle (xor within 32-lane groups; constants are the
// documented ISA wave-reduction patterns -- cdna4_isa.md "Common patterns")
template <int PAT>
__device__ __forceinline__ float swz(float x) {
    return __int_as_float(__builtin_amdgcn_ds_swizzle(__float_as_int(x), PAT));
}
#define SWZ_X1  0x041F
#define SWZ_X2  0x081F
#define SWZ_X4  0x101F
#define SWZ_X8  0x201F
#define SWZ_X16 0x401F

// ---- ws layout (floats), all pre-scaled by log2e / 2log2e ----
#define WS_W1   0
#define WS_W2A  4096
#define WS_W2B  6144
#define WS_WX   7168
#define WS_B1   7296
#define WS_B2   7424
#define WS_N    7488

__device__ __forceinline__ float scale1(int r) {
    return (r >= 64 && r < 96) ? TWOLOG2E : LOG2E;
}
__device__ __forceinline__ float scale2(int r) {
    return ((r >> 4) == 2) ? TWOLOG2E : LOG2E;
}

__global__ __launch_bounds__(256) void prescale_kernel(
    const float* __restrict__ W_ih1, const float* __restrict__ W_hh1,
    const float* __restrict__ b_ih1, const float* __restrict__ b_hh1,
    const float* __restrict__ W_ih2, const float* __restrict__ W_hh2,
    const float* __restrict__ b_ih2, const float* __restrict__ b_hh2,
    float* __restrict__ ws)
{
    const int i = blockIdx.x * 256 + threadIdx.x;
    if (i >= WS_N) return;
    float v;
    if (i < WS_W2A) {
        v = W_hh1[i] * scale1(i >> 5);
    } else if (i < WS_W2B) {
        const int j = i - WS_W2A;
        v = W_ih2[j] * scale2(j >> 5);
    } else if (i < WS_WX) {
        const int j = i - WS_W2B;
        v = W_hh2[j] * scale2(j >> 4);
    } else if (i < WS_B1) {
        const int r = i - WS_WX;
        v = W_ih1[r] * scale1(r);
    } else if (i < WS_B2) {
        const int r = i - WS_B1;
        v = (b_ih1[r] + b_hh1[r]) * scale1(r);
    } else {
        const int r = i - WS_B2;
        v = (b_ih2[r] + b_hh2[r]) * scale2(r);
    }
    ws[i] = v;
}

__global__ __launch_bounds__(64 * RPB, 2) void lstm_deep_kernel(
    const float* __restrict__ x,
    const float* __restrict__ ws,     // pre-scaled weights/biases
    const float* __restrict__ W_out,
    const float* __restrict__ b_out,
    float* __restrict__ out)
{
    const int tid  = threadIdx.x;
    const int lane = tid & 63;
    const int wid  = tid >> 6;                        // wave within block
    const int row0 = (blockIdx.x * RPB + wid) * RPW;  // 2 rows per wave
    const int row1 = row0 + 1;

    // ONLY LDS: per-wave, per-row h1 slices (h2 lives in SGPRs)
    __shared__ __align__(16) float sh1[RPB][RPW][H1_];

    const int ga = lane;        // layer1 rows: i (low) / f (high)
    const int gb = 64 + lane;   // layer1 rows: g (low, tanh) / o (high)

    const f32x2* W1p  = reinterpret_cast<const f32x2*>(ws + WS_W1);
    const f32x2* W2ap = reinterpret_cast<const f32x2*>(ws + WS_W2A);
    const f32x4* W2b4 = reinterpret_cast<const f32x4*>(ws + WS_W2B);

    f32x2 w1a[H1_ / 2], w1b[H1_ / 2];
    #pragma unroll
    for (int j = 0; j < H1_ / 2; ++j) {
        w1a[j] = W1p[ga * (H1_ / 2) + j];
        w1b[j] = W1p[gb * (H1_ / 2) + j];
    }
    f32x2 w2a[H1_ / 2];
    #pragma unroll
    for (int j = 0; j < H1_ / 2; ++j) w2a[j] = W2ap[lane * (H1_ / 2) + j];
    float w2bs[H2_];   // scalar: paired with SGPR h2 operand in v_fmac
    #pragma unroll
    for (int q = 0; q < H2_ / 4; ++q) {
        const f32x4 v = W2b4[lane * (H2_ / 4) + q];
        w2bs[4 * q + 0] = v.x; w2bs[4 * q + 1] = v.y;
        w2bs[4 * q + 2] = v.z; w2bs[4 * q + 3] = v.w;
    }

    float wxa = ws[WS_WX + ga];
    float wxb = ws[WS_WX + gb];
    float ba  = ws[WS_B1 + ga];
    float bb  = ws[WS_B1 + gb];
    float b2  = ws[WS_B2 + lane];

    // one-time opaque pin (R14/R15-proven: keeps weights resident, no remat)
    #pragma unroll
    for (int j = 0; j < H1_ / 2; ++j)
        asm volatile("" : "+v"(w1a[j]), "+v"(w1b[j]), "+v"(w2a[j]));
    #pragma unroll
    for (int k = 0; k < H2_; ++k)
        asm volatile("" : "+v"(w2bs[k]));
    asm volatile("" : "+v"(wxa), "+v"(wxb), "+v"(ba), "+v"(bb), "+v"(b2));

    const bool  low  = (lane < 32);
    const int   gt   = lane >> 4;
    const float sc1b = low ? 2.0f : 1.0f;
    const float of1b = low ? -1.0f : 0.0f;
    const float sc2c = (gt == 2) ? 2.0f : 1.0f;
    const float of2c = (gt == 2) ? -1.0f : 0.0f;

    const int   u2   = lane & 15;
    const float wout = W_out[u2];
    const float bout = b_out[0];

    // ---- state ----
    float c1_0 = 0.0f, c1_1 = 0.0f;   // valid in high lanes (unit lane-32)
    float c2_0 = 0.0f, c2_1 = 0.0f;   // valid in lanes 0..15 (unit u2)
    float h2s0[H2_], h2s1[H2_];       // h2_{t-1}, wave-uniform (SGPRs)
    #pragma unroll
    for (int k = 0; k < H2_; ++k) { h2s0[k] = 0.0f; h2s1[k] = 0.0f; }
    if (lane < H1_) { sh1[wid][0][lane] = 0.0f; sh1[wid][1][lane] = 0.0f; }
    FENCE_HW();   // init visible before first-step reads (wave-local)

    const f32x4* __restrict__ xr0 = reinterpret_cast<const f32x4*>(x + (size_t)row0 * T_);
    const f32x4* __restrict__ xr1 = reinterpret_cast<const f32x4*>(x + (size_t)row1 * T_);
    float*       __restrict__ or0 = out + (size_t)row0 * T_;
    float*       __restrict__ or1 = out + (size_t)row1 * T_;

    // carried layer-1 gate accumulators, pre-seeded for t=0 (h1_{-1}=0)
    f32x4 xv0 = xr0[0];
    f32x4 xv1 = xr1[0];
    f32x2 A0c = {__builtin_fmaf(wxa, xv0.x, ba), 0.0f};
    f32x2 B0c = {__builtin_fmaf(wxb, xv0.x, bb), 0.0f};
    f32x2 A1c = {__builtin_fmaf(wxa, xv1.x, ba), 0.0f};
    f32x2 B1c = {__builtin_fmaf(wxb, xv1.x, bb), 0.0f};

    // one timestep for BOTH rows. nxt* = x of NEXT step (pipelined layer-1).
    auto step2 = [&](float nxt0, float nxt1, float& yp0, float& yp1) {
        // ---- layer-1 activations from CARRIED accumulators (step starts hot) ----
        const float acca0 = A0c.x + A0c.y, accb0 = B0c.x + B0c.y;
        const float acca1 = A1c.x + A1c.y, accb1 = B1c.x + B1c.y;

        const float sa0 = sig_core(acca0);
        const float sa1 = sig_core(acca1);
        const float sb0 = __builtin_fmaf(sc1b, sig_core(accb0), of1b);
        const float sb1 = __builtin_fmaf(sc1b, sig_core(accb1), of1b);
        const float pv0 = __shfl_xor(sa0 * sb0, 32);   // R15-proven (permlane reverted)
        const float pv1 = __shfl_xor(sa1 * sb1, 32);
        c1_0 = __builtin_fmaf(sa0, c1_0, pv0);
        c1_1 = __builtin_fmaf(sa1, c1_1, pv1);
        const float tc10 = __builtin_fmaf(2.0f, sig_core(TWOLOG2E * c1_0), -1.0f);
        const float tc11 = __builtin_fmaf(2.0f, sig_core(TWOLOG2E * c1_1), -1.0f);
        const float h1n0 = sb0 * tc10;   // valid lanes 32..63
        const float h1n1 = sb1 * tc11;

        if (lane >= 32) {
            sh1[wid][0][lane - 32] = h1n0;
            sh1[wid][1][lane - 32] = h1n1;
        }

        // ---- layer-2 h2-part: scalar v_fmac with SGPR h2 operand (no packing) ----
        float e00 = 0.0f, e01 = 0.0f, e02 = 0.0f, e03 = 0.0f;
        float e10 = 0.0f, e11 = 0.0f, e12 = 0.0f, e13 = 0.0f;
        #pragma unroll
        for (int k = 0; k < H2_; k += 4) {
            e00 = __builtin_fmaf(w2bs[k + 0], h2s0[k + 0], e00);
            e01 = __builtin_fmaf(w2bs[k + 1], h2s0[k + 1], e01);
            e02 = __builtin_fmaf(w2bs[k + 2], h2s0[k + 2], e02);
            e03 = __builtin_fmaf(w2bs[k + 3], h2s0[k + 3], e03);
            e10 = __builtin_fmaf(w2bs[k + 0], h2s1[k + 0], e10);
            e11 = __builtin_fmaf(w2bs[k + 1], h2s1[k + 1], e11);
            e12 = __builtin_fmaf(w2bs[k + 2], h2s1[k + 2], e12);
            e13 = __builtin_fmaf(w2bs[k + 3], h2s1[k + 3], e13);
        }
        const float eh0 = (e00 + e01) + (e02 + e03);
        const float eh1 = (e10 + e11) + (e12 + e13);

        FENCE_HW();   // sh1 writes complete; no sh1 read hoisted above

        // refill carried layer-1 accumulators with NEXT step's x
        A0c = f32x2{__builtin_fmaf(wxa, nxt0, ba), 0.0f};
        B0c = f32x2{__builtin_fmaf(wxb, nxt0, bb), 0.0f};
        A1c = f32x2{__builtin_fmaf(wxa, nxt1, ba), 0.0f};
        B1c = f32x2{__builtin_fmaf(wxb, nxt1, bb), 0.0f};

        // ---- SINGLE sh1 read region: layer-2 h1-part AND next-step layer-1 ----
        f32x2 E0 = {b2, 0.0f}, F0 = {0.0f, 0.0f};
        f32x2 E1 = {b2, 0.0f}, F1 = {0.0f, 0.0f};
        {
            const f32x4* p0 = reinterpret_cast<const f32x4*>(sh1[wid][0]);
            const f32x4* p1 = reinterpret_cast<const f32x4*>(sh1[wid][1]);
            #pragma unroll
            for (int q = 0; q < H1_ / 4; ++q) {
                const f32x4 v0 = p0[q];
                const f32x4 v1 = p1[q];
                const f32x2 a01 = {v0.x, v0.y}, a23 = {v0.z, v0.w};
                const f32x2 b01 = {v1.x, v1.y}, b23 = {v1.z, v1.w};
                PKFMA(E0,  w2a[2 * q],     a01);
                PKFMA(F0,  w2a[2 * q + 1], a23);
                PKFMA(E1,  w2a[2 * q],     b01);
                PKFMA(F1,  w2a[2 * q + 1], b23);
                PKFMA(A0c, w1a[2 * q],     a01);
                PKFMA(A0c, w1a[2 * q + 1], a23);
                PKFMA(B0c, w1b[2 * q],     a01);
                PKFMA(B0c, w1b[2 * q + 1], a23);
                PKFMA(A1c, w1a[2 * q],     b01);
                PKFMA(A1c, w1a[2 * q + 1], b23);
                PKFMA(B1c, w1b[2 * q],     b01);
                PKFMA(B1c, w1b[2 * q + 1], b23);
            }
        }
        const float d20 = ((E0.x + E0.y) + (F0.x + F0.y)) + eh0;
        const float d21 = ((E1.x + E1.y) + (F1.x + F1.y)) + eh1;

        const float s20 = __builtin_fmaf(sc2c, sig_core(d20), of2c);
        const float s21 = __builtin_fmaf(sc2c, sig_core(d21), of2c);
        // gate combine in lanes 0..15: shfl_xor32 (proven) + documented swizzle16
        const float s2sw0 = __shfl_xor(s20, 32);   // lanes 0-15: g-gate
        const float s2sw1 = __shfl_xor(s21, 32);
        const float t320  = s20 * s2sw0;           // i*g
        const float t321  = s21 * s2sw1;
        const float sf0   = swz<SWZ_X16>(s20);     // f-gate
        const float sf1   = swz<SWZ_X16>(s21);
        const float so0   = swz<SWZ_X16>(s2sw0);   // o-gate (xor48 = xor32 . xor16)
        const float so1   = swz<SWZ_X16>(s2sw1);

        c2_0 = __builtin_fmaf(sf0, c2_0, t320);
        c2_1 = __builtin_fmaf(sf1, c2_1, t321);
        const float tc20 = __builtin_fmaf(2.0f, sig_core(TWOLOG2E * c2_0), -1.0f);
        const float tc21 = __builtin_fmaf(2.0f, sig_core(TWOLOG2E * c2_1), -1.0f);
        const float h2v0 = so0 * tc20;   // valid lanes 0..15
        const float h2v1 = so1 * tc21;

        // h2 -> SGPRs for next step (readlane ignores exec; lanes 0..15 valid)
        #pragma unroll
        for (int k = 0; k < H2_; ++k) {
            h2s0[k] = lane_bcast(h2v0, k);
            h2s1[k] = lane_bcast(h2v1, k);
        }
        FENCE_SW();   // step boundary: no cross-step LDS reorder (zero instr)

        yp0 = wout * h2v0;   // garbage in lanes >=16; group-0 reduce discards
        yp1 = wout * h2v1;
    };

    #pragma unroll 1
    for (int t4 = 0; t4 < T_ / 4; ++t4) {
        const int nx = (t4 + 1 < T_ / 4) ? (t4 + 1) : t4;
        const f32x4 xn0 = xr0[nx];    // prefetch next 4 inputs, both rows
        const f32x4 xn1 = xr1[nx];

        float p00, p10, p01, p11, p02, p12, p03, p13;
        step2(xv0.y, xv1.y, p00, p10);   // step 4t+0; preps A for 4t+1
        step2(xv0.z, xv1.z, p01, p11);
        step2(xv0.w, xv1.w, p02, p12);
        step2(xn0.x, xn1.x, p03, p13);   // step 4t+3; preps A for 4(t+1)

        // 8 interleaved 16-lane xor reductions via documented literal swizzles
        p00 += swz<SWZ_X1>(p00);  p10 += swz<SWZ_X1>(p10);
        p01 += swz<SWZ_X1>(p01);  p11 += swz<SWZ_X1>(p11);
        p02 += swz<SWZ_X1>(p02);  p12 += swz<SWZ_X1>(p12);
        p03 += swz<SWZ_X1>(p03);  p13 += swz<SWZ_X1>(p13);
        p00 += swz<SWZ_X2>(p00);  p10 += swz<SWZ_X2>(p10);
        p01 += swz<SWZ_X2>(p01);  p11 += swz<SWZ_X2>(p11);
        p02 += swz<SWZ_X2>(p02);  p12 += swz<SWZ_X2>(p12);
        p03 += swz<SWZ_X2>(p03);  p13 += swz<SWZ_X2>(p13);
        p00 += swz<SWZ_X4>(p00);  p10 += swz<SWZ_X4>(p10);
        p01 += swz<SWZ_X4>(p01);  p11 += swz<SWZ_X4>(p11);
        p02 += swz<SWZ_X4>(p02);  p12 += swz<SWZ_X4>(p12);
        p03 += swz<SWZ_X4>(p03);  p13 += swz<SWZ_X4>(p13);
        p00 += swz<SWZ_X8>(p00);  p10 += swz<SWZ_X8>(p10);
        p01 += swz<SWZ_X8>(p01);  p11 += swz<SWZ_X8>(p11);
        p02 += swz<SWZ_X8>(p02);  p12 += swz<SWZ_X8>(p12);
        p03 += swz<SWZ_X8>(p03);  p13 += swz<SWZ_X8>(p13);

        if (lane == 0) {
            f32x4 y0 = {p00 + bout, p01 + bout, p02 + bout, p03 + bout};
            f32x4 y1 = {p10 + bout, p11 + bout, p12 + bout, p13 + bout};
            *reinterpret_cast<f32x4*>(or0 + 4 * t4) = y0;
            *reinterpret_cast<f32x4*>(or1 + 4 * t4) = y1;
        }
        xv0 = xn0;
        xv1 = xn1;
    }
}

extern "C" void kernel_launch(void* const* d_in, const int* in_sizes, int n_in,
                              void* d_out, int out_size, void* d_ws, size_t ws_size,
                              hipStream_t stream) {
    const float* xp     = (const float*)d_in[0];
    const float* W_ih1  = (const float*)d_in[1];
    const float* W_hh1  = (const float*)d_in[2];
    const float* b_ih1  = (const float*)d_in[3];
    const float* b_hh1  = (const float*)d_in[4];
    const float* W_ih2  = (const float*)d_in[5];
    const float* W_hh2  = (const float*)d_in[6];
    const float* b_ih2  = (const float*)d_in[7];
    const float* b_hh2  = (const float*)d_in[8];
    const float* W_out  = (const float*)d_in[9];
    const float* b_out  = (const float*)d_in[10];
    float* out = (float*)d_out;
    float* ws  = (float*)d_ws;

    prescale_kernel<<<(WS_N + 255) / 256, 256, 0, stream>>>(
        W_ih1, W_hh1, b_ih1, b_hh1, W_ih2, W_hh2, b_ih2, b_hh2, ws);

    dim3 grid(B_ / (RPB * RPW));
    dim3 block(64 * RPB);
    lstm_deep_kernel<<<grid, block, 0, stream>>>(xp, ws, W_out, b_out, out);
}

// Round 19
// 2212.089 us; speedup vs baseline: 1.0399x; 1.0380x over previous
//
#include <hip/hip_runtime.h>

#define B_  4096
#define T_  2048
#define H1_ 32
#define H2_ 16
#define RPB 4   // waves per block (256 threads); waves never interact
#define RPW 2   // independent rows per wave (R11-proven best)

#define LOG2E     1.44269504088896340736f
#define TWOLOG2E  2.88539008177792681472f

typedef float f32x2 __attribute__((ext_vector_type(2)));
typedef float f32x4 __attribute__((ext_vector_type(4)));

// packed fp32 fma (R5-proven exact; lowers to v_pk_fma_f32)
#if defined(__has_builtin)
#if __has_builtin(__builtin_elementwise_fma)
#define PKFMA(acc, a, b) (acc) = __builtin_elementwise_fma((a), (b), (acc))
#endif
#endif
#ifndef PKFMA
#define PKFMA(acc, a, b) (acc) = (a) * (b) + (acc)
#endif

// Wave-local LDS ordering fences (R9/R11/R14/R15-proven)
#define FENCE_HW() asm volatile("s_waitcnt lgkmcnt(0)" ::: "memory")
#define FENCE_SW() asm volatile("" ::: "memory")

__device__ __forceinline__ float sig_core(float z) {
    return __builtin_amdgcn_rcpf(1.0f + __builtin_amdgcn_exp2f(-z));
}
// wave-uniform broadcast: physical-lane read -> SGPR (R15-proven)
__device__ __forceinline__ float lane_bcast(float v, int srcLane) {
    return __uint_as_float(__builtin_amdgcn_readlane(__float_as_uint(v), srcLane));
}

// ---- ws layout (floats), all pre-scaled by log2e / 2log2e ----
#define WS_W1   0
#define WS_W2A  4096
#define WS_W2B  6144
#define WS_WX   7168
#define WS_B1   7296
#define WS_B2   7424
#define WS_N    7488

__device__ __forceinline__ float scale1(int r) {
    return (r >= 64 && r < 96) ? TWOLOG2E : LOG2E;
}
__device__ __forceinline__ float scale2(int r) {
    return ((r >> 4) == 2) ? TWOLOG2E : LOG2E;
}

__global__ __launch_bounds__(256) void prescale_kernel(
    const float* __restrict__ W_ih1, const float* __restrict__ W_hh1,
    const float* __restrict__ b_ih1, const float* __restrict__ b_hh1,
    const float* __restrict__ W_ih2, const float* __restrict__ W_hh2,
    const float* __restrict__ b_ih2, const float* __restrict__ b_hh2,
    float* __restrict__ ws)
{
    const int i = blockIdx.x * 256 + threadIdx.x;
    if (i >= WS_N) return;
    float v;
    if (i < WS_W2A) {
        v = W_hh1[i] * scale1(i >> 5);
    } else if (i < WS_W2B) {
        const int j = i - WS_W2A;
        v = W_ih2[j] * scale2(j >> 5);
    } else if (i < WS_WX) {
        const int j = i - WS_W2B;
        v = W_hh2[j] * scale2(j >> 4);
    } else if (i < WS_B1) {
        const int r = i - WS_WX;
        v = W_ih1[r] * scale1(r);
    } else if (i < WS_B2) {
        const int r = i - WS_B1;
        v = (b_ih1[r] + b_hh1[r]) * scale1(r);
    } else {
        const int r = i - WS_B2;
        v = (b_ih2[r] + b_hh2[r]) * scale2(r);
    }
    ws[i] = v;
}

__global__ __launch_bounds__(64 * RPB, 2) void lstm_deep_kernel(
    const float* __restrict__ x,
    const float* __restrict__ ws,     // pre-scaled weights/biases
    const float* __restrict__ W_out,
    const float* __restrict__ b_out,
    float* __restrict__ out)
{
    const int tid  = threadIdx.x;
    const int lane = tid & 63;
    const int wid  = tid >> 6;                        // wave within block
    const int row0 = (blockIdx.x * RPB + wid) * RPW;  // 2 rows per wave
    const int row1 = row0 + 1;

    // ONLY LDS: per-wave, per-row h1 slices (h2 lives in SGPRs)
    __shared__ __align__(16) float sh1[RPB][RPW][H1_];

    const int ga = lane;        // layer1 rows: i (low) / f (high)
    const int gb = 64 + lane;   // layer1 rows: g (low, tanh) / o (high)

    const f32x2* W1p  = reinterpret_cast<const f32x2*>(ws + WS_W1);
    const f32x2* W2ap = reinterpret_cast<const f32x2*>(ws + WS_W2A);
    const f32x2* W2bp = reinterpret_cast<const f32x2*>(ws + WS_W2B);

    f32x2 w1a[H1_ / 2], w1b[H1_ / 2];
    #pragma unroll
    for (int j = 0; j < H1_ / 2; ++j) {
        w1a[j] = W1p[ga * (H1_ / 2) + j];
        w1b[j] = W1p[gb * (H1_ / 2) + j];
    }
    f32x2 w2a[H1_ / 2];
    #pragma unroll
    for (int j = 0; j < H1_ / 2; ++j) w2a[j] = W2ap[lane * (H1_ / 2) + j];
    f32x2 w2b[H2_ / 2];
    #pragma unroll
    for (int j = 0; j < H2_ / 2; ++j) w2b[j] = W2bp[lane * (H2_ / 2) + j];

    float wxa = ws[WS_WX + ga];
    float wxb = ws[WS_WX + gb];
    float ba  = ws[WS_B1 + ga];
    float bb  = ws[WS_B1 + gb];
    float b2  = ws[WS_B2 + lane];

    // one-time opaque pin (R14/R15-proven: keeps weights resident, no remat)
    #pragma unroll
    for (int j = 0; j < H1_ / 2; ++j)
        asm volatile("" : "+v"(w1a[j]), "+v"(w1b[j]), "+v"(w2a[j]));
    #pragma unroll
    for (int j = 0; j < H2_ / 2; ++j)
        asm volatile("" : "+v"(w2b[j]));
    asm volatile("" : "+v"(wxa), "+v"(wxb), "+v"(ba), "+v"(bb), "+v"(b2));

    const bool  low  = (lane < 32);
    const int   gt   = lane >> 4;
    const float sc1b = low ? 2.0f : 1.0f;
    const float of1b = low ? -1.0f : 0.0f;
    const float sc2c = (gt == 2) ? 2.0f : 1.0f;
    const float of2c = (gt == 2) ? -1.0f : 0.0f;

    const int   u2   = lane & 15;
    const float wout = W_out[u2];
    const float bout = b_out[0];

    // ---- state ----
    float c1_0 = 0.0f, c1_1 = 0.0f;   // valid in high lanes (unit lane-32)
    float c2_0 = 0.0f, c2_1 = 0.0f;   // valid in lanes 0..15 (unit u2)
    float h2s0[H2_], h2s1[H2_];       // h2_{t-1}, wave-uniform (SGPRs)
    #pragma unroll
    for (int k = 0; k < H2_; ++k) { h2s0[k] = 0.0f; h2s1[k] = 0.0f; }
    if (lane < H1_) { sh1[wid][0][lane] = 0.0f; sh1[wid][1][lane] = 0.0f; }
    FENCE_HW();   // init visible before first-step reads (wave-local)

    const f32x4* __restrict__ xr0 = reinterpret_cast<const f32x4*>(x + (size_t)row0 * T_);
    const f32x4* __restrict__ xr1 = reinterpret_cast<const f32x4*>(x + (size_t)row1 * T_);
    float*       __restrict__ or0 = out + (size_t)row0 * T_;
    float*       __restrict__ or1 = out + (size_t)row1 * T_;

    // carried layer-1 gate accumulators, pre-seeded for t=0 (h1_{-1}=0)
    f32x4 xv0 = xr0[0];
    f32x4 xv1 = xr1[0];
    f32x2 A0c = {__builtin_fmaf(wxa, xv0.x, ba), 0.0f};
    f32x2 B0c = {__builtin_fmaf(wxb, xv0.x, bb), 0.0f};
    f32x2 A1c = {__builtin_fmaf(wxa, xv1.x, ba), 0.0f};
    f32x2 B1c = {__builtin_fmaf(wxb, xv1.x, bb), 0.0f};

    // one timestep for BOTH rows. nxt* = x of NEXT step (pipelined layer-1).
    auto step2 = [&](float nxt0, float nxt1, float& yp0, float& yp1) {
        // ---- layer-1 activations from CARRIED accumulators (step starts hot) ----
        const float acca0 = A0c.x + A0c.y, accb0 = B0c.x + B0c.y;
        const float acca1 = A1c.x + A1c.y, accb1 = B1c.x + B1c.y;

        const float sa0 = sig_core(acca0);
        const float sa1 = sig_core(acca1);
        const float sb0 = __builtin_fmaf(sc1b, sig_core(accb0), of1b);
        const float sb1 = __builtin_fmaf(sc1b, sig_core(accb1), of1b);
        const float pv0 = __shfl_xor(sa0 * sb0, 32);
        const float pv1 = __shfl_xor(sa1 * sb1, 32);
        c1_0 = __builtin_fmaf(sa0, c1_0, pv0);
        c1_1 = __builtin_fmaf(sa1, c1_1, pv1);
        const float tc10 = __builtin_fmaf(2.0f, sig_core(TWOLOG2E * c1_0), -1.0f);
        const float tc11 = __builtin_fmaf(2.0f, sig_core(TWOLOG2E * c1_1), -1.0f);
        const float h1n0 = sb0 * tc10;   // valid lanes 32..63
        const float h1n1 = sb1 * tc11;

        if (lane >= 32) {
            sh1[wid][0][lane - 32] = h1n0;
            sh1[wid][1][lane - 32] = h1n1;
        }

        // ---- layer-2 h2-part from SGPR-resident h2_{t-1} (R15 form) ----
        f32x2 E0 = {b2, 0.0f}, F0 = {0.0f, 0.0f};
        f32x2 E1 = {b2, 0.0f}, F1 = {0.0f, 0.0f};
        #pragma unroll
        for (int q = 0; q < H2_ / 4; ++q) {
            const f32x2 hA0 = {h2s0[4 * q],     h2s0[4 * q + 1]};
            const f32x2 hB0 = {h2s0[4 * q + 2], h2s0[4 * q + 3]};
            const f32x2 hA1 = {h2s1[4 * q],     h2s1[4 * q + 1]};
            const f32x2 hB1 = {h2s1[4 * q + 2], h2s1[4 * q + 3]};
            PKFMA(E0, w2b[2 * q],     hA0);
            PKFMA(F0, w2b[2 * q + 1], hB0);
            PKFMA(E1, w2b[2 * q],     hA1);
            PKFMA(F1, w2b[2 * q + 1], hB1);
        }

        FENCE_HW();   // sh1 writes complete; no sh1 read hoisted above

        // refill carried layer-1 accumulators with NEXT step's x
        A0c = f32x2{__builtin_fmaf(wxa, nxt0, ba), 0.0f};
        B0c = f32x2{__builtin_fmaf(wxb, nxt0, bb), 0.0f};
        A1c = f32x2{__builtin_fmaf(wxa, nxt1, ba), 0.0f};
        B1c = f32x2{__builtin_fmaf(wxb, nxt1, bb), 0.0f};

        // ---- SINGLE sh1 read region: layer-2 h1-part AND next-step layer-1 ----
        {
            const f32x4* p0 = reinterpret_cast<const f32x4*>(sh1[wid][0]);
            const f32x4* p1 = reinterpret_cast<const f32x4*>(sh1[wid][1]);
            #pragma unroll
            for (int q = 0; q < H1_ / 4; ++q) {
                const f32x4 v0 = p0[q];
                const f32x4 v1 = p1[q];
                const f32x2 a01 = {v0.x, v0.y}, a23 = {v0.z, v0.w};
                const f32x2 b01 = {v1.x, v1.y}, b23 = {v1.z, v1.w};
                PKFMA(E0,  w2a[2 * q],     a01);
                PKFMA(F0,  w2a[2 * q + 1], a23);
                PKFMA(E1,  w2a[2 * q],     b01);
                PKFMA(F1,  w2a[2 * q + 1], b23);
                PKFMA(A0c, w1a[2 * q],     a01);
                PKFMA(A0c, w1a[2 * q + 1], a23);
                PKFMA(B0c, w1b[2 * q],     a01);
                PKFMA(B0c, w1b[2 * q + 1], a23);
                PKFMA(A1c, w1a[2 * q],     b01);
                PKFMA(A1c, w1a[2 * q + 1], b23);
                PKFMA(B1c, w1b[2 * q],     b01);
                PKFMA(B1c, w1b[2 * q + 1], b23);
            }
        }
        const float d20 = (E0.x + E0.y) + (F0.x + F0.y);
        const float d21 = (E1.x + E1.y) + (F1.x + F1.y);

        const float s20 = __builtin_fmaf(sc2c, sig_core(d20), of2c);
        const float s21 = __builtin_fmaf(sc2c, sig_core(d21), of2c);
        // gate combine, valid in lanes 0..15 (R15-proven)
        const float t320 = s20 * __shfl_xor(s20, 32);
        const float t321 = s21 * __shfl_xor(s21, 32);
        const float sf0  = __shfl_xor(s20, 16), sf1 = __shfl_xor(s21, 16);
        const float so0  = __shfl_xor(s20, 48), so1 = __shfl_xor(s21, 48);

        c2_0 = __builtin_fmaf(sf0, c2_0, t320);
        c2_1 = __builtin_fmaf(sf1, c2_1, t321);
        const float tc20 = __builtin_fmaf(2.0f, sig_core(TWOLOG2E * c2_0), -1.0f);
        const float tc21 = __builtin_fmaf(2.0f, sig_core(TWOLOG2E * c2_1), -1.0f);
        const float h2v0 = so0 * tc20;   // valid lanes 0..15
        const float h2v1 = so1 * tc21;

        // h2 -> SGPRs for next step (readlane ignores exec; lanes 0..15 valid)
        #pragma unroll
        for (int k = 0; k < H2_; ++k) {
            h2s0[k] = lane_bcast(h2v0, k);
            h2s1[k] = lane_bcast(h2v1, k);
        }
        FENCE_SW();   // step boundary: no cross-step LDS reorder (zero instr)

        yp0 = wout * h2v0;   // garbage in lanes >=16; group-0 reduce discards
        yp1 = wout * h2v1;
    };

    // ---- iteration 0 (peeled): fill q partials, no reduce yet ----
    float q00, q10, q01, q11, q02, q12, q03, q13;
    {
        const f32x4 xn0 = xr0[1];
        const f32x4 xn1 = xr1[1];
        step2(xv0.y, xv1.y, q00, q10);
        step2(xv0.z, xv1.z, q01, q11);
        step2(xv0.w, xv1.w, q02, q12);
        step2(xn0.x, xn1.x, q03, q13);
        xv0 = xn0;
        xv1 = xn1;
    }

    // ---- main loop: current steps interleaved with PREVIOUS iteration's
    //      y-reduce stages (independent work fills step-chain bubbles) ----
    #pragma unroll 1
    for (int t4 = 1; t4 < T_ / 4; ++t4) {
        const int nx = (t4 + 1 < T_ / 4) ? (t4 + 1) : t4;
        const f32x4 xn0 = xr0[nx];
        const f32x4 xn1 = xr1[nx];

        float p00, p10, p01, p11, p02, p12, p03, p13;
        step2(xv0.y, xv1.y, p00, p10);
        q00 += __shfl_xor(q00, 1);  q10 += __shfl_xor(q10, 1);   // stage 1
        q01 += __shfl_xor(q01, 1);  q11 += __shfl_xor(q11, 1);
        q02 += __shfl_xor(q02, 1);  q12 += __shfl_xor(q12, 1);
        q03 += __shfl_xor(q03, 1);  q13 += __shfl_xor(q13, 1);
        step2(xv0.z, xv1.z, p01, p11);
        q00 += __shfl_xor(q00, 2);  q10 += __shfl_xor(q10, 2);   // stage 2
        q01 += __shfl_xor(q01, 2);  q11 += __shfl_xor(q11, 2);
        q02 += __shfl_xor(q02, 2);  q12 += __shfl_xor(q12, 2);
        q03 += __shfl_xor(q03, 2);  q13 += __shfl_xor(q13, 2);
        step2(xv0.w, xv1.w, p02, p12);
        q00 += __shfl_xor(q00, 4);  q10 += __shfl_xor(q10, 4);   // stage 3
        q01 += __shfl_xor(q01, 4);  q11 += __shfl_xor(q11, 4);
        q02 += __shfl_xor(q02, 4);  q12 += __shfl_xor(q12, 4);
        q03 += __shfl_xor(q03, 4);  q13 += __shfl_xor(q13, 4);
        step2(xn0.x, xn1.x, p03, p13);
        q00 += __shfl_xor(q00, 8);  q10 += __shfl_xor(q10, 8);   // stage 4
        q01 += __shfl_xor(q01, 8);  q11 += __shfl_xor(q11, 8);
        q02 += __shfl_xor(q02, 8);  q12 += __shfl_xor(q12, 8);
        q03 += __shfl_xor(q03, 8);  q13 += __shfl_xor(q13, 8);

        if (lane == 0) {
            f32x4 y0 = {q00 + bout, q01 + bout, q02 + bout, q03 + bout};
            f32x4 y1 = {q10 + bout, q11 + bout, q12 + bout, q13 + bout};
            *reinterpret_cast<f32x4*>(or0 + 4 * (t4 - 1)) = y0;
            *reinterpret_cast<f32x4*>(or1 + 4 * (t4 - 1)) = y1;
        }
        q00 = p00; q10 = p10; q01 = p01; q11 = p11;
        q02 = p02; q12 = p12; q03 = p03; q13 = p13;
        xv0 = xn0;
        xv1 = xn1;
    }

    // ---- epilogue: reduce + store last iteration's partials ----
    #pragma unroll
    for (int off = 1; off <= 8; off <<= 1) {
        q00 += __shfl_xor(q00, off);  q10 += __shfl_xor(q10, off);
        q01 += __shfl_xor(q01, off);  q11 += __shfl_xor(q11, off);
        q02 += __shfl_xor(q02, off);  q12 += __shfl_xor(q12, off);
        q03 += __shfl_xor(q03, off);  q13 += __shfl_xor(q13, off);
    }
    if (lane == 0) {
        f32x4 y0 = {q00 + bout, q01 + bout, q02 + bout, q03 + bout};
        f32x4 y1 = {q10 + bout, q11 + bout, q12 + bout, q13 + bout};
        *reinterpret_cast<f32x4*>(or0 + (T_ - 4)) = y0;
        *reinterpret_cast<f32x4*>(or1 + (T_ - 4)) = y1;
    }
}

extern "C" void kernel_launch(void* const* d_in, const int* in_sizes, int n_in,
                              void* d_out, int out_size, void* d_ws, size_t ws_size,
                              hipStream_t stream) {
    const float* xp     = (const float*)d_in[0];
    const float* W_ih1  = (const float*)d_in[1];
    const float* W_hh1  = (const float*)d_in[2];
    const float* b_ih1  = (const float*)d_in[3];
    const float* b_hh1  = (const float*)d_in[4];
    const float* W_ih2  = (const float*)d_in[5];
    const float* W_hh2  = (const float*)d_in[6];
    const float* b_ih2  = (const float*)d_in[7];
    const float* b_hh2  = (const float*)d_in[8];
    const float* W_out  = (const float*)d_in[9];
    const float* b_out  = (const float*)d_in[10];
    float* out = (float*)d_out;
    float* ws  = (float*)d_ws;

    prescale_kernel<<<(WS_N + 255) / 256, 256, 0, stream>>>(
        W_ih1, W_hh1, b_ih1, b_hh1, W_ih2, W_hh2, b_ih2, b_hh2, ws);

    dim3 grid(B_ / (RPB * RPW));
    dim3 block(64 * RPB);
    lstm_deep_kernel<<<grid, block, 0, stream>>>(xp, ws, W_out, b_out, out);
}

// Round 20
// 2211.638 us; speedup vs baseline: 1.0401x; 1.0002x over previous
//
#include <hip/hip_runtime.h>

#define B_  4096
#define T_  2048
#define H1_ 32
#define H2_ 16
#define RPB 4   // waves per block (256 threads); waves never interact
#define RPW 2   // independent rows per wave (R11-proven best)

#define LOG2E     1.44269504088896340736f
#define TWOLOG2E  2.88539008177792681472f

typedef float f32x2 __attribute__((ext_vector_type(2)));
typedef float f32x4 __attribute__((ext_vector_type(4)));

// packed fp32 fma (R5-proven exact; lowers to v_pk_fma_f32)
#if defined(__has_builtin)
#if __has_builtin(__builtin_elementwise_fma)
#define PKFMA(acc, a, b) (acc) = __builtin_elementwise_fma((a), (b), (acc))
#endif
#endif
#ifndef PKFMA
#define PKFMA(acc, a, b) (acc) = (a) * (b) + (acc)
#endif

// Wave-local LDS ordering fences:
// FENCE_HW: compiler fence + lgkmcnt(0) drain (used once, outside the loop).
// FENCE_SW: ZERO-instruction compiler memory barrier. In-loop ordering relies
//   on the per-wave in-order DS pipe: a wave's ds_write -> ds_read to the same
//   address is ordered by hardware; the compiler's own use-site lgkmcnt waits
//   cover the data dependency. R8 failed because it had NO fence (compiler
//   hoisted reads above writes); the HW drain R9 added was stronger than
//   needed and stalls ~50-60 cyc/step.
#define FENCE_HW() asm volatile("s_waitcnt lgkmcnt(0)" ::: "memory")
#define FENCE_SW() asm volatile("" ::: "memory")

__device__ __forceinline__ float sig_core(float z) {
    return __builtin_amdgcn_rcpf(1.0f + __builtin_amdgcn_exp2f(-z));
}
// wave-uniform broadcast: physical-lane read -> SGPR (R15-proven)
__device__ __forceinline__ float lane_bcast(float v, int srcLane) {
    return __uint_as_float(__builtin_amdgcn_readlane(__float_as_uint(v), srcLane));
}

// ---- ws layout (floats), all pre-scaled by log2e / 2log2e ----
#define WS_W1   0
#define WS_W2A  4096
#define WS_W2B  6144
#define WS_WX   7168
#define WS_B1   7296
#define WS_B2   7424
#define WS_N    7488

__device__ __forceinline__ float scale1(int r) {
    return (r >= 64 && r < 96) ? TWOLOG2E : LOG2E;
}
__device__ __forceinline__ float scale2(int r) {
    return ((r >> 4) == 2) ? TWOLOG2E : LOG2E;
}

__global__ __launch_bounds__(256) void prescale_kernel(
    const float* __restrict__ W_ih1, const float* __restrict__ W_hh1,
    const float* __restrict__ b_ih1, const float* __restrict__ b_hh1,
    const float* __restrict__ W_ih2, const float* __restrict__ W_hh2,
    const float* __restrict__ b_ih2, const float* __restrict__ b_hh2,
    float* __restrict__ ws)
{
    const int i = blockIdx.x * 256 + threadIdx.x;
    if (i >= WS_N) return;
    float v;
    if (i < WS_W2A) {
        v = W_hh1[i] * scale1(i >> 5);
    } else if (i < WS_W2B) {
        const int j = i - WS_W2A;
        v = W_ih2[j] * scale2(j >> 5);
    } else if (i < WS_WX) {
        const int j = i - WS_W2B;
        v = W_hh2[j] * scale2(j >> 4);
    } else if (i < WS_B1) {
        const int r = i - WS_WX;
        v = W_ih1[r] * scale1(r);
    } else if (i < WS_B2) {
        const int r = i - WS_B1;
        v = (b_ih1[r] + b_hh1[r]) * scale1(r);
    } else {
        const int r = i - WS_B2;
        v = (b_ih2[r] + b_hh2[r]) * scale2(r);
    }
    ws[i] = v;
}

__global__ __launch_bounds__(64 * RPB, 2) void lstm_deep_kernel(
    const float* __restrict__ x,
    const float* __restrict__ ws,     // pre-scaled weights/biases
    const float* __restrict__ W_out,
    const float* __restrict__ b_out,
    float* __restrict__ out)
{
    const int tid  = threadIdx.x;
    const int lane = tid & 63;
    const int wid  = tid >> 6;                        // wave within block
    const int row0 = (blockIdx.x * RPB + wid) * RPW;  // 2 rows per wave
    const int row1 = row0 + 1;

    // ONLY LDS: per-wave, per-row h1 slices (h2 lives in SGPRs)
    __shared__ __align__(16) float sh1[RPB][RPW][H1_];

    const int ga = lane;        // layer1 rows: i (low) / f (high)
    const int gb = 64 + lane;   // layer1 rows: g (low, tanh) / o (high)

    const f32x2* W1p  = reinterpret_cast<const f32x2*>(ws + WS_W1);
    const f32x2* W2ap = reinterpret_cast<const f32x2*>(ws + WS_W2A);
    const f32x2* W2bp = reinterpret_cast<const f32x2*>(ws + WS_W2B);

    f32x2 w1a[H1_ / 2], w1b[H1_ / 2];
    #pragma unroll
    for (int j = 0; j < H1_ / 2; ++j) {
        w1a[j] = W1p[ga * (H1_ / 2) + j];
        w1b[j] = W1p[gb * (H1_ / 2) + j];
    }
    f32x2 w2a[H1_ / 2];
    #pragma unroll
    for (int j = 0; j < H1_ / 2; ++j) w2a[j] = W2ap[lane * (H1_ / 2) + j];
    f32x2 w2b[H2_ / 2];
    #pragma unroll
    for (int j = 0; j < H2_ / 2; ++j) w2b[j] = W2bp[lane * (H2_ / 2) + j];

    float wxa = ws[WS_WX + ga];
    float wxb = ws[WS_WX + gb];
    float ba  = ws[WS_B1 + ga];
    float bb  = ws[WS_B1 + gb];
    float b2  = ws[WS_B2 + lane];

    // one-time opaque pin (R14/R15-proven: keeps weights resident, no remat)
    #pragma unroll
    for (int j = 0; j < H1_ / 2; ++j)
        asm volatile("" : "+v"(w1a[j]), "+v"(w1b[j]), "+v"(w2a[j]));
    #pragma unroll
    for (int j = 0; j < H2_ / 2; ++j)
        asm volatile("" : "+v"(w2b[j]));
    asm volatile("" : "+v"(wxa), "+v"(wxb), "+v"(ba), "+v"(bb), "+v"(b2));

    const bool  low  = (lane < 32);
    const int   gt   = lane >> 4;
    const float sc1b = low ? 2.0f : 1.0f;
    const float of1b = low ? -1.0f : 0.0f;
    const float sc2c = (gt == 2) ? 2.0f : 1.0f;
    const float of2c = (gt == 2) ? -1.0f : 0.0f;

    const int   u2   = lane & 15;
    const float wout = W_out[u2];
    const float bout = b_out[0];

    // ---- state ----
    float c1_0 = 0.0f, c1_1 = 0.0f;   // valid in high lanes (unit lane-32)
    float c2_0 = 0.0f, c2_1 = 0.0f;   // valid in lanes 0..15 (unit u2)
    float h2s0[H2_], h2s1[H2_];       // h2_{t-1}, wave-uniform (SGPRs)
    #pragma unroll
    for (int k = 0; k < H2_; ++k) { h2s0[k] = 0.0f; h2s1[k] = 0.0f; }
    if (lane < H1_) { sh1[wid][0][lane] = 0.0f; sh1[wid][1][lane] = 0.0f; }
    FENCE_HW();   // one-time: init visible before first-step reads

    const f32x4* __restrict__ xr0 = reinterpret_cast<const f32x4*>(x + (size_t)row0 * T_);
    const f32x4* __restrict__ xr1 = reinterpret_cast<const f32x4*>(x + (size_t)row1 * T_);
    float*       __restrict__ or0 = out + (size_t)row0 * T_;
    float*       __restrict__ or1 = out + (size_t)row1 * T_;

    // carried layer-1 gate accumulators, pre-seeded for t=0 (h1_{-1}=0)
    f32x4 xv0 = xr0[0];
    f32x4 xv1 = xr1[0];
    f32x2 A0c = {__builtin_fmaf(wxa, xv0.x, ba), 0.0f};
    f32x2 B0c = {__builtin_fmaf(wxb, xv0.x, bb), 0.0f};
    f32x2 A1c = {__builtin_fmaf(wxa, xv1.x, ba), 0.0f};
    f32x2 B1c = {__builtin_fmaf(wxb, xv1.x, bb), 0.0f};

    // one timestep for BOTH rows. nxt* = x of NEXT step (pipelined layer-1).
    auto step2 = [&](float nxt0, float nxt1, float& yp0, float& yp1) {
        // ---- layer-1 activations from CARRIED accumulators (step starts hot) ----
        const float acca0 = A0c.x + A0c.y, accb0 = B0c.x + B0c.y;
        const float acca1 = A1c.x + A1c.y, accb1 = B1c.x + B1c.y;

        const float sa0 = sig_core(acca0);
        const float sa1 = sig_core(acca1);
        const float sb0 = __builtin_fmaf(sc1b, sig_core(accb0), of1b);
        const float sb1 = __builtin_fmaf(sc1b, sig_core(accb1), of1b);
        const float pv0 = __shfl_xor(sa0 * sb0, 32);
        const float pv1 = __shfl_xor(sa1 * sb1, 32);
        c1_0 = __builtin_fmaf(sa0, c1_0, pv0);
        c1_1 = __builtin_fmaf(sa1, c1_1, pv1);
        const float tc10 = __builtin_fmaf(2.0f, sig_core(TWOLOG2E * c1_0), -1.0f);
        const float tc11 = __builtin_fmaf(2.0f, sig_core(TWOLOG2E * c1_1), -1.0f);
        const float h1n0 = sb0 * tc10;   // valid lanes 32..63
        const float h1n1 = sb1 * tc11;

        if (lane >= 32) {
            sh1[wid][0][lane - 32] = h1n0;
            sh1[wid][1][lane - 32] = h1n1;
        }

        // ---- layer-2 h2-part from SGPR-resident h2_{t-1} (R15 form) ----
        f32x2 E0 = {b2, 0.0f}, F0 = {0.0f, 0.0f};
        f32x2 E1 = {b2, 0.0f}, F1 = {0.0f, 0.0f};
        #pragma unroll
        for (int q = 0; q < H2_ / 4; ++q) {
            const f32x2 hA0 = {h2s0[4 * q],     h2s0[4 * q + 1]};
            const f32x2 hB0 = {h2s0[4 * q + 2], h2s0[4 * q + 3]};
            const f32x2 hA1 = {h2s1[4 * q],     h2s1[4 * q + 1]};
            const f32x2 hB1 = {h2s1[4 * q + 2], h2s1[4 * q + 3]};
            PKFMA(E0, w2b[2 * q],     hA0);
            PKFMA(F0, w2b[2 * q + 1], hB0);
            PKFMA(E1, w2b[2 * q],     hA1);
            PKFMA(F1, w2b[2 * q + 1], hB1);
        }

        // Compiler-only fence: ds_writes above may NOT be hoisted below /
        // ds_reads below may NOT be hoisted above. HW per-wave DS FIFO
        // orders write->read; no lgkmcnt drain needed (the R9 stall).
        FENCE_SW();

        // refill carried layer-1 accumulators with NEXT step's x
        A0c = f32x2{__builtin_fmaf(wxa, nxt0, ba), 0.0f};
        B0c = f32x2{__builtin_fmaf(wxb, nxt0, bb), 0.0f};
        A1c = f32x2{__builtin_fmaf(wxa, nxt1, ba), 0.0f};
        B1c = f32x2{__builtin_fmaf(wxb, nxt1, bb), 0.0f};

        // ---- SINGLE sh1 read region: layer-2 h1-part AND next-step layer-1 ----
        {
            const f32x4* p0 = reinterpret_cast<const f32x4*>(sh1[wid][0]);
            const f32x4* p1 = reinterpret_cast<const f32x4*>(sh1[wid][1]);
            #pragma unroll
            for (int q = 0; q < H1_ / 4; ++q) {
                const f32x4 v0 = p0[q];
                const f32x4 v1 = p1[q];
                const f32x2 a01 = {v0.x, v0.y}, a23 = {v0.z, v0.w};
                const f32x2 b01 = {v1.x, v1.y}, b23 = {v1.z, v1.w};
                PKFMA(E0,  w2a[2 * q],     a01);
                PKFMA(F0,  w2a[2 * q + 1], a23);
                PKFMA(E1,  w2a[2 * q],     b01);
                PKFMA(F1,  w2a[2 * q + 1], b23);
                PKFMA(A0c, w1a[2 * q],     a01);
                PKFMA(A0c, w1a[2 * q + 1], a23);
                PKFMA(B0c, w1b[2 * q],     a01);
                PKFMA(B0c, w1b[2 * q + 1], a23);
                PKFMA(A1c, w1a[2 * q],     b01);
                PKFMA(A1c, w1a[2 * q + 1], b23);
                PKFMA(B1c, w1b[2 * q],     b01);
                PKFMA(B1c, w1b[2 * q + 1], b23);
            }
        }
        const float d20 = (E0.x + E0.y) + (F0.x + F0.y);
        const float d21 = (E1.x + E1.y) + (F1.x + F1.y);

        const float s20 = __builtin_fmaf(sc2c, sig_core(d20), of2c);
        const float s21 = __builtin_fmaf(sc2c, sig_core(d21), of2c);
        // gate combine, valid in lanes 0..15 (R15-proven)
        const float t320 = s20 * __shfl_xor(s20, 32);
        const float t321 = s21 * __shfl_xor(s21, 32);
        const float sf0  = __shfl_xor(s20, 16), sf1 = __shfl_xor(s21, 16);
        const float so0  = __shfl_xor(s20, 48), so1 = __shfl_xor(s21, 48);

        c2_0 = __builtin_fmaf(sf0, c2_0, t320);
        c2_1 = __builtin_fmaf(sf1, c2_1, t321);
        const float tc20 = __builtin_fmaf(2.0f, sig_core(TWOLOG2E * c2_0), -1.0f);
        const float tc21 = __builtin_fmaf(2.0f, sig_core(TWOLOG2E * c2_1), -1.0f);
        const float h2v0 = so0 * tc20;   // valid lanes 0..15
        const float h2v1 = so1 * tc21;

        // h2 -> SGPRs for next step (readlane ignores exec; lanes 0..15 valid)
        #pragma unroll
        for (int k = 0; k < H2_; ++k) {
            h2s0[k] = lane_bcast(h2v0, k);
            h2s1[k] = lane_bcast(h2v1, k);
        }
        FENCE_SW();   // step boundary: no cross-step LDS reorder (zero instr)

        yp0 = wout * h2v0;   // garbage in lanes >=16; group-0 reduce discards
        yp1 = wout * h2v1;
    };

    // ---- iteration 0 (peeled): fill q partials, no reduce yet ----
    float q00, q10, q01, q11, q02, q12, q03, q13;
    {
        const f32x4 xn0 = xr0[1];
        const f32x4 xn1 = xr1[1];
        step2(xv0.y, xv1.y, q00, q10);
        step2(xv0.z, xv1.z, q01, q11);
        step2(xv0.w, xv1.w, q02, q12);
        step2(xn0.x, xn1.x, q03, q13);
        xv0 = xn0;
        xv1 = xn1;
    }

    // ---- main loop: current steps interleaved with PREVIOUS iteration's
    //      y-reduce stages (independent work fills step-chain bubbles) ----
    #pragma unroll 1
    for (int t4 = 1; t4 < T_ / 4; ++t4) {
        const int nx = (t4 + 1 < T_ / 4) ? (t4 + 1) : t4;
        const f32x4 xn0 = xr0[nx];
        const f32x4 xn1 = xr1[nx];

        float p00, p10, p01, p11, p02, p12, p03, p13;
        step2(xv0.y, xv1.y, p00, p10);
        q00 += __shfl_xor(q00, 1);  q10 += __shfl_xor(q10, 1);   // stage 1
        q01 += __shfl_xor(q01, 1);  q11 += __shfl_xor(q11, 1);
        q02 += __shfl_xor(q02, 1);  q12 += __shfl_xor(q12, 1);
        q03 += __shfl_xor(q03, 1);  q13 += __shfl_xor(q13, 1);
        step2(xv0.z, xv1.z, p01, p11);
        q00 += __shfl_xor(q00, 2);  q10 += __shfl_xor(q10, 2);   // stage 2
        q01 += __shfl_xor(q01, 2);  q11 += __shfl_xor(q11, 2);
        q02 += __shfl_xor(q02, 2);  q12 += __shfl_xor(q12, 2);
        q03 += __shfl_xor(q03, 2);  q13 += __shfl_xor(q13, 2);
        step2(xv0.w, xv1.w, p02, p12);
        q00 += __shfl_xor(q00, 4);  q10 += __shfl_xor(q10, 4);   // stage 3
        q01 += __shfl_xor(q01, 4);  q11 += __shfl_xor(q11, 4);
        q02 += __shfl_xor(q02, 4);  q12 += __shfl_xor(q12, 4);
        q03 += __shfl_xor(q03, 4);  q13 += __shfl_xor(q13, 4);
        step2(xn0.x, xn1.x, p03, p13);
        q00 += __shfl_xor(q00, 8);  q10 += __shfl_xor(q10, 8);   // stage 4
        q01 += __shfl_xor(q01, 8);  q11 += __shfl_xor(q11, 8);
        q02 += __shfl_xor(q02, 8);  q12 += __shfl_xor(q12, 8);
        q03 += __shfl_xor(q03, 8);  q13 += __shfl_xor(q13, 8);

        if (lane == 0) {
            f32x4 y0 = {q00 + bout, q01 + bout, q02 + bout, q03 + bout};
            f32x4 y1 = {q10 + bout, q11 + bout, q12 + bout, q13 + bout};
            *reinterpret_cast<f32x4*>(or0 + 4 * (t4 - 1)) = y0;
            *reinterpret_cast<f32x4*>(or1 + 4 * (t4 - 1)) = y1;
        }
        q00 = p00; q10 = p10; q01 = p01; q11 = p11;
        q02 = p02; q12 = p12; q03 = p03; q13 = p13;
        xv0 = xn0;
        xv1 = xn1;
    }

    // ---- epilogue: reduce + store last iteration's partials ----
    #pragma unroll
    for (int off = 1; off <= 8; off <<= 1) {
        q00 += __shfl_xor(q00, off);  q10 += __shfl_xor(q10, off);
        q01 += __shfl_xor(q01, off);  q11 += __shfl_xor(q11, off);
        q02 += __shfl_xor(q02, off);  q12 += __shfl_xor(q12, off);
        q03 += __shfl_xor(q03, off);  q13 += __shfl_xor(q13, off);
    }
    if (lane == 0) {
        f32x4 y0 = {q00 + bout, q01 + bout, q02 + bout, q03 + bout};
        f32x4 y1 = {q10 + bout, q11 + bout, q12 + bout, q13 + bout};
        *reinterpret_cast<f32x4*>(or0 + (T_ - 4)) = y0;
        *reinterpret_cast<f32x4*>(or1 + (T_ - 4)) = y1;
    }
}

extern "C" void kernel_launch(void* const* d_in, const int* in_sizes, int n_in,
                              void* d_out, int out_size, void* d_ws, size_t ws_size,
                              hipStream_t stream) {
    const float* xp     = (const float*)d_in[0];
    const float* W_ih1  = (const float*)d_in[1];
    const float* W_hh1  = (const float*)d_in[2];
    const float* b_ih1  = (const float*)d_in[3];
    const float* b_hh1  = (const float*)d_in[4];
    const float* W_ih2  = (const float*)d_in[5];
    const float* W_hh2  = (const float*)d_in[6];
    const float* b_ih2  = (const float*)d_in[7];
    const float* b_hh2  = (const float*)d_in[8];
    const float* W_out  = (const float*)d_in[9];
    const float* b_out  = (const float*)d_in[10];
    float* out = (float*)d_out;
    float* ws  = (float*)d_ws;

    prescale_kernel<<<(WS_N + 255) / 256, 256, 0, stream>>>(
        W_ih1, W_hh1, b_ih1, b_hh1, W_ih2, W_hh2, b_ih2, b_hh2, ws);

    dim3 grid(B_ / (RPB * RPW));
    dim3 block(64 * RPB);
    lstm_deep_kernel<<<grid, block, 0, stream>>>(xp, ws, W_out, b_out, out);
}